// Round 8
// baseline (224.910 us; speedup 1.0000x reference)
//
#include <hip/hip_runtime.h>
#include <hip/hip_bf16.h>
#include <hip/hip_cooperative_groups.h>

namespace cg = cooperative_groups;

// x: (N=8, C=512, T=32, H=14, W=14) fp32 contiguous = 131072 rows x 196 floats.
// Cooperative fused kernel. Block b owns 64 consecutive rows (2 channels x 32 t,
// one contiguous 50 KB slab). Phase 1: quad-scheme GAP (4 threads/row, strided
// float4, 2x shfl_xor) -> plain stores to gap[]. grid.sync() (driver-provided
// cross-XCD fences + co-residency guarantee). Phase 2: wave 0 computes the
// 5-tap channel conv + sigmoid for its 64 rows from gap (LLC-resident).
// Host falls back to the proven two-kernel path if cooperative launch fails.

#define F4_PER_ROW 49
#define ROWS_PB 64
#define F4_PB (ROWS_PB * F4_PER_ROW)   // 3136

__device__ __forceinline__ float quad_gap_sum(const float4* __restrict__ p, int q) {
    // p points at this thread's first float4 (row base + q). Strided by 4 float4s.
    float4 a0 = p[0];
    float4 a1 = p[4];
    #pragma unroll
    for (int i = 2; i < 12; i += 2) {
        float4 u = p[4 * i];
        float4 v = p[4 * (i + 1)];
        a0.x += u.x; a0.y += u.y; a0.z += u.z; a0.w += u.w;
        a1.x += v.x; a1.y += v.y; a1.z += v.z; a1.w += v.w;
    }
    float sum = ((a0.x + a1.x) + (a0.y + a1.y)) + ((a0.z + a1.z) + (a0.w + a1.w));
    if (q == 0) {
        float4 u = p[48];
        sum += (u.x + u.y) + (u.z + u.w);
    }
    sum += __shfl_xor(sum, 1, 64);
    sum += __shfl_xor(sum, 2, 64);
    return sum;
}

__global__ __launch_bounds__(256, 8) void fused_coop_kernel(
        const float* __restrict__ x,
        const float* __restrict__ w,
        float* __restrict__ out,
        float* __restrict__ gap) {
    const int b   = blockIdx.x;
    const int tid = threadIdx.x;
    const int s   = tid >> 2;
    const int q   = tid & 3;

    // ---- Phase 1: GAP over own contiguous slab ----
    const float4* p = reinterpret_cast<const float4*>(x) +
                      (size_t)b * F4_PB + s * F4_PER_ROW + q;
    float sum = quad_gap_sum(p, q);
    if (q == 0) gap[b * ROWS_PB + s] = sum * (1.0f / 196.0f);

    cg::this_grid().sync();

    // ---- Phase 2: wave 0, one output per thread ----
    if (tid >= ROWS_PB) return;

    const int c0 = (2 * b) & 511;       // first owned channel within its n
    const int rr = b * ROWS_PB + tid;   // output row
    const int cc = c0 + (tid >> 5);     // channel of this row

    const float w0 = w[0], w1 = w[1], w2 = w[2], w3 = w[3], w4 = w[4];

    float acc = w2 * gap[rr];
    if (cc >= 2)   acc += w0 * gap[rr - 64];
    if (cc >= 1)   acc += w1 * gap[rr - 32];
    if (cc <= 510) acc += w3 * gap[rr + 32];
    if (cc <= 509) acc += w4 * gap[rr + 64];

    out[rr] = 1.0f / (1.0f + __expf(-acc));
}

// ---------------- fallback path (proven R5 structure) ----------------

__global__ __launch_bounds__(256) void gap_kernel(
        const float* __restrict__ x,
        float* __restrict__ gap) {
    const int tid = threadIdx.x;
    const int s = tid >> 2;
    const int q = tid & 3;
    const float4* p = reinterpret_cast<const float4*>(x) +
                      (size_t)blockIdx.x * F4_PB + s * F4_PER_ROW + q;
    float sum = quad_gap_sum(p, q);
    if (q == 0)
        gap[(size_t)blockIdx.x * ROWS_PB + s] = sum * (1.0f / 196.0f);
}

__global__ void conv_sig_kernel(const float* __restrict__ gap,
                                const float* __restrict__ w,
                                float* __restrict__ out,
                                int N, int C, int T) {
    const int idx = blockIdx.x * blockDim.x + threadIdx.x;
    const int total = N * C * T;
    if (idx >= total) return;

    const int t = idx % T;
    const int c = (idx / T) % C;
    const int n = idx / (T * C);

    const float w0 = w[0], w1 = w[1], w2 = w[2], w3 = w[3], w4 = w[4];

    const float* g = gap + ((size_t)n * C) * T + t;
    float acc = w2 * g[c * T];
    if (c >= 2)      acc += w0 * g[(c - 2) * T];
    if (c >= 1)      acc += w1 * g[(c - 1) * T];
    if (c + 1 < C)   acc += w3 * g[(c + 1) * T];
    if (c + 2 < C)   acc += w4 * g[(c + 2) * T];

    out[idx] = 1.0f / (1.0f + __expf(-acc));
}

extern "C" void kernel_launch(void* const* d_in, const int* in_sizes, int n_in,
                              void* d_out, int out_size, void* d_ws, size_t ws_size,
                              hipStream_t stream) {
    const float* x = (const float*)d_in[0];   // 8*512*32*14*14
    const float* w = (const float*)d_in[1];   // 5
    float* out = (float*)d_out;               // 8*512*32 = 131072
    float* gap = (float*)d_ws;                // 131072 floats

    const int total_rows = 8 * 512 * 32;          // 131072
    const int blocks = total_rows / ROWS_PB;      // 2048

    void* args[] = {(void*)&x, (void*)&w, (void*)&out, (void*)&gap};
    hipError_t e = hipLaunchCooperativeKernel((const void*)fused_coop_kernel,
                                              dim3(blocks), dim3(256),
                                              args, 0, stream);
    if (e != hipSuccess) {
        (void)hipGetLastError();   // clear sticky error, take fallback
        gap_kernel<<<blocks, 256, 0, stream>>>(x, gap);
        const int threadsB = 256;
        const int blocksB = (total_rows + threadsB - 1) / threadsB;
        conv_sig_kernel<<<blocksB, threadsB, 0, stream>>>(gap, w, out, 8, 512, 32);
    }
}

// Round 9
// 23.023 us; speedup vs baseline: 9.7690x; 9.7690x over previous
//
#include <hip/hip_runtime.h>
#include <hip/hip_bf16.h>

// x: (N=8, C=512, T=32, H=14, W=14) fp32 contiguous = 131072 rows x 196 floats.
// Single fused kernel, NO cross-block sync: halo recompute.
// Block = (n, 32 owned channels, 2 timesteps): 8*16*16 = 2048 blocks, 256 thr.
// Phase 1: GAP for (32+4 halo) channels x 2 t = 72 rows; 4 threads per row
//   (quad scheme: strided float4, 2x shfl_xor), 2 passes of 64 rows -> LDS[72].
//   Channels outside [0,512) contribute 0 (zero padding of the conv).
// Phase 2: threads 0..63 compute the 5-tap channel conv + sigmoid from LDS
//   (entirely intra-block thanks to halo) and write out. No d_ws use.
// Halo re-read = 4/32 = 12.5%, mostly L2/LLC-absorbed (neighbor-in-channel
// blocks are 16 apart in blockIdx -> same XCD under %8 round-robin).

#define F4_PER_ROW 49
#define CH 32
#define TBLK 2
#define HALO 2
#define ROWS_TOT ((CH + 2 * HALO) * TBLK)   // 72

__global__ __launch_bounds__(256, 8) void fused_halo_kernel(
        const float* __restrict__ x,
        const float* __restrict__ w,
        float* __restrict__ out) {
    const int bid = blockIdx.x;
    const int n   = bid >> 8;          // 256 blocks per image
    const int cb  = (bid >> 4) & 15;   // channel tile
    const int tb  = bid & 15;          // t tile
    const int c0  = cb * CH;
    const int t0  = tb * TBLK;

    const int tid = threadIdx.x;
    const int q   = tid & 3;

    __shared__ float gs[ROWS_TOT];     // [ (halo_ci) * TBLK + tj ]

    #pragma unroll
    for (int pass = 0; pass < 2; ++pass) {
        const int ri = pass * 64 + (tid >> 2);
        if (ri < ROWS_TOT) {
            const int ci = ri >> 1;            // 0..35 (c = c0-2+ci)
            const int tj = ri & 1;
            const int c  = c0 - HALO + ci;
            float sum = 0.0f;
            if (c >= 0 && c < 512) {
                const int row = (n * 512 + c) * 32 + t0 + tj;
                const float4* p = reinterpret_cast<const float4*>(x) +
                                  (size_t)row * F4_PER_ROW + q;
                float4 a0 = p[0];
                float4 a1 = p[4];
                #pragma unroll
                for (int i = 2; i < 12; i += 2) {
                    float4 u = p[4 * i];
                    float4 v = p[4 * (i + 1)];
                    a0.x += u.x; a0.y += u.y; a0.z += u.z; a0.w += u.w;
                    a1.x += v.x; a1.y += v.y; a1.z += v.z; a1.w += v.w;
                }
                sum = ((a0.x + a1.x) + (a0.y + a1.y)) +
                      ((a0.z + a1.z) + (a0.w + a1.w));
                if (q == 0) {
                    float4 u = p[48];
                    sum += (u.x + u.y) + (u.z + u.w);
                }
            }
            sum += __shfl_xor(sum, 1, 64);
            sum += __shfl_xor(sum, 2, 64);
            if (q == 0) gs[ri] = sum * (1.0f / 196.0f);
        }
    }
    __syncthreads();

    // Phase 2: 64 outputs (32 channels x 2 t), one per thread.
    if (tid < CH * TBLK) {
        const int ci = tid >> 1;   // owned channel index 0..31
        const int tj = tid & 1;
        const float acc =
            w[0] * gs[(ci + 0) * TBLK + tj] +
            w[1] * gs[(ci + 1) * TBLK + tj] +
            w[2] * gs[(ci + 2) * TBLK + tj] +
            w[3] * gs[(ci + 3) * TBLK + tj] +
            w[4] * gs[(ci + 4) * TBLK + tj];
        out[(n * 512 + c0 + ci) * 32 + t0 + tj] = 1.0f / (1.0f + __expf(-acc));
    }
}

extern "C" void kernel_launch(void* const* d_in, const int* in_sizes, int n_in,
                              void* d_out, int out_size, void* d_ws, size_t ws_size,
                              hipStream_t stream) {
    const float* x = (const float*)d_in[0];   // 8*512*32*14*14
    const float* w = (const float*)d_in[1];   // 5
    float* out = (float*)d_out;               // 8*512*32

    fused_halo_kernel<<<2048, 256, 0, stream>>>(x, w, out);
}